// Round 11
// baseline (589.509 us; speedup 1.0000x reference)
//
#include <hip/hip_runtime.h>

// VQ-VAE vector-quantize, fused: distances + argmin + gather + loss.
// x: [65536, 256] fp32, dict: [256, 1024] fp32.
// out: q_ste [65536*256] fp32, then loss scalar at out[65536*256].
//
// NUMERICS (bit-exact vs np reference, verified absmax 0.0 R2-R15 — DO NOT CHANGE):
//  - row norm ||f||^2: np pairwise tree (two INDEPENDENT 128-halves, each an
//    8-accumulator r8[e&7] chain, unfused squares, fixed combine tree,
//    result = half0_tree + half1_tree; 0+sq == sq so zero-init is exact)
//  - enorm ||e||^2: sequential d ascending, unfused square then plain add
//  - dist = fl( fl(A + B) - 2*s ), argmin first-index on exact ties
//  - STE out = fl(x + fl(q - x)); loss on pure q, (1+BETA)/(N*D) scale
//  - per-(row,code) dot chain: d strictly ascending (c0 outer, ddl inner
//    = dd 0..15), fmaf each step — textually R12's chain.
//
// PERF (R15 -> R16): pk-math was a null (scalar v_fma already runs at the full
// 157.3TF SIMD-32 rate). Ledger: 462us = 284 VALU (218 FMA floor + 66 other)
// + ~180 stall. The stall source is STAGE_FX's zero-distance global_load ->
// vmcnt -> ds_write, every step, every wave (T14 fixes it but spills: R6/R11).
// R16 = spill-free T14: stage x via global_load_lds DMA (0 VGPR, 0 ds_writes)
// as 16B granules (row,d-quad), T21-correct XOR swizzle:
//   slot(row,c0) = (c0*128+row) ^ ((row>>3)&3)   [linear DMA dest,
//   pre-swizzled per-lane global src, same XOR on read]
// -> conflict-free ds_read_b128 on the f-side (4 ty-groups -> disjoint bank
// quads). Compute nest c0{8 f-reads; ddl{4 e-reads; 128 FMA}} — same LDS-read
// count as R12, region size matches R12's unroll-4 (R13 lesson: no full-step
// unroll). Issue->wait distance now = full compute phase (m97 pattern).

#define NROWS 65536
#define DDIM  256
#define KC    1024
#define BM    128            // rows per block
#define BC    256            // codes per ct tile
#define DC    16             // d-chunk per pipeline step
#define NDC   16             // DDIM/DC
#define NCT   4              // KC/BC
#define NSTEP 64             // NCT*NDC

typedef float v4 __attribute__((ext_vector_type(4)));

#define GLOAD_LDS16(gp, lp) __builtin_amdgcn_global_load_lds( \
    (const __attribute__((address_space(1))) void*)(gp),      \
    (__attribute__((address_space(3))) void*)(lp), 16, 0, 0)

// x chunk [128 rows][16 d] via async DMA: 512 granules of 16B (one d-quad of
// one row). Lane writes linear slot sp = wave*128 + i*64 + lane; the granule
// fetched is g = sp ^ ((sp>>3)&3) (involution), so slot(row,c0) =
// (c0*128+row) ^ ((row>>3)&3). Zero VGPR staging, no ds_writes.
#define STAGE_FX_DMA(dstbuf, dc_) do {                                          \
    _Pragma("unroll")                                                           \
    for (int i_ = 0; i_ < 2; ++i_) {                                            \
        int sp_ = ((tid >> 6) * 2 + i_) * 64 + (tid & 63);                      \
        int g_  = sp_ ^ ((sp_ >> 3) & 3);                                       \
        int row_ = g_ & 127, c0_ = g_ >> 7;                                     \
        GLOAD_LDS16(&x[(size_t)(rowbase + row_) * DDIM + (dc_) * DC + c0_ * 4], \
                    (dstbuf) + sp_ * 4);                                        \
    }                                                                           \
} while (0)

// dict tile [16 d][256 codes] via async DMA: lds dest = uniform + lane*16.
#define STAGE_DICT(pbuf, ct_, dc_) do {                                         \
    _Pragma("unroll")                                                           \
    for (int i_ = 0; i_ < 4; ++i_) {                                            \
        int flat_ = i_ * 256 + tid;                                             \
        int dd_ = flat_ >> 6;            /* wave-uniform */                     \
        int l4_ = (flat_ & 63) * 4;      /* lane*4 floats = lane*16 B */        \
        GLOAD_LDS16(&dict[(size_t)((dc_) * DC + dd_) * KC + (ct_) * BC + l4_],  \
                    (pbuf) + dd_ * BC + l4_);                                   \
    }                                                                           \
} while (0)

// Pre-kernel: codebook column norms (np order: rounded square then plain add,
// sequential d ascending) + transposed codebook + loss zero-init.
// 16 blocks x 64 threads: 16 CUs on the latency-bound chains.
__global__ __launch_bounds__(64) void vq_prep(const float* __restrict__ dict,
                                              float* __restrict__ enorm,
                                              float* __restrict__ dictT,
                                              float* __restrict__ loss) {
#pragma clang fp contract(off)
    int k = blockIdx.x * 64 + threadIdx.x;
    if (k == 0) *loss = 0.f;   // runs before vq_main (stream order)
    float s = 0.f;
    #pragma unroll 8
    for (int d = 0; d < DDIM; ++d) {
        float v = dict[(size_t)d * KC + k];
        float sq = v * v;          // rounded square (np temp array)
        s = s + sq;                // plain add, NOT fma (chain stays sequential)
        dictT[(size_t)k * DDIM + d] = v;
    }
    enorm[k] = s;
}

__global__ __launch_bounds__(256, 2) void vq_main(const float* __restrict__ x,
                                                  const float* __restrict__ dict,
                                                  const float* __restrict__ enorm,
                                                  const float* __restrict__ dictT,
                                                  float* __restrict__ out,
                                                  float* __restrict__ loss) {
    __shared__ float fXb[2][512 * 4];    // 8 KB each (512 granules)
    __shared__ float dTs[2][DC * BC];    // 16 KB each
    __shared__ float rnormS[BM];         // 0.5 KB -> total 48.5 KB, 2 blk/CU

    const int tid = threadIdx.x;
    const int tx  = tid & 15;            // 16 code-groups x 16 codes = 256
    const int ty  = tid >> 4;            // 16 row-groups  x  8 rows  = 128
    const int rowbase = blockIdx.x * BM;

    // ---- Prologue. Step-0 staging DMA first (overlaps the rnorm reads).
    STAGE_DICT(&dTs[0][0], 0, 0);
    STAGE_FX_DMA(&fXb[0][0], 0);

    // Block-local row norms: verified np two-half chain, 2 threads/row over
    // this block's 128 rows. Regs scoped -> dead before the main loop.
    {
#pragma clang fp contract(off)
        const int row  = tid >> 1;
        const int half = tid & 1;
        const float* xr = x + (size_t)(rowbase + row) * DDIM + half * 128;
        float r8[8] = {0.f, 0.f, 0.f, 0.f, 0.f, 0.f, 0.f, 0.f};
        #pragma unroll 8
        for (int c = 0; c < 32; ++c) {   // local e = 4c..4c+3 ; e&7 == (c&1)*4+k
            float4 v = *(const float4*)&xr[c * 4];
            int b = (c & 1) * 4;
            float s0 = v.x * v.x; r8[b + 0] = r8[b + 0] + s0;
            float s1 = v.y * v.y; r8[b + 1] = r8[b + 1] + s1;
            float s2 = v.z * v.z; r8[b + 2] = r8[b + 2] + s2;
            float s3 = v.w * v.w; r8[b + 3] = r8[b + 3] + s3;
        }
        float h = ((r8[0] + r8[1]) + (r8[2] + r8[3]))
                + ((r8[4] + r8[5]) + (r8[6] + r8[7]));
        float ho = __shfl_down(h, 1, 64);    // odd lane's half-1 tree
        if (half == 0) rnormS[row] = h + ho; // fl(half0 + half1) — verified chain
    }

    __syncthreads();                     // drains DMA + publishes rnormS

    // Row norms (broadcast reads: 16 lanes share ty). row = 8*ty+r.
    float Arow[8];
    #pragma unroll
    for (int r = 0; r < 8; ++r) Arow[r] = rnormS[ty * 8 + r];

    float minv[8];
    int   mini[8];
    #pragma unroll
    for (int r = 0; r < 8; ++r) { minv[r] = 3.4e38f; mini[r] = 0; }

    // f-read addressing: thread's rows live at slots
    // (c0*128 + ty*8 + (r^(ty&3))); in float units:
    // c0*512 + fbx + ((r*4) ^ sws), fbx = ty*32, sws = (ty&3)*4.
    const int fbx = ty * 32;
    const int sws = (ty & 3) * 4;

    float acc[8][16];
    // ---- Main: 64 steps, one barrier each. DMA staging issued at step top;
    // its vmcnt drain (inside __syncthreads) lands after ~4000 cyc of FMA.
    #pragma unroll 2                     // compile-time buffer parity
    for (int s = 0; s < NSTEP; ++s) {
        const int p = s & 1;
        if (s < NSTEP - 1) {
            const int ns = s + 1;
            STAGE_DICT(&dTs[1 - p][0], ns >> 4, ns & 15);   // async, 0 regs
            STAGE_FX_DMA(&fXb[1 - p][0], ns & 15);          // async, 0 regs
        }
        if ((s & 15) == 0) {
            #pragma unroll
            for (int r = 0; r < 8; ++r)
                #pragma unroll
                for (int j = 0; j < 16; ++j) acc[r][j] = 0.f;
        }
        // d = c0*4 + ddl consumed strictly ascending (frozen chain order).
        #pragma unroll 1                 // region = 4 dd, matches R12's unroll-4
        for (int c0 = 0; c0 < 4; ++c0) {
            v4 fq[8];
            #pragma unroll
            for (int r = 0; r < 8; ++r)
                fq[r] = *(const v4*)&fXb[p][c0 * 512 + fbx + ((r * 4) ^ sws)];
            #pragma unroll
            for (int ddl = 0; ddl < 4; ++ddl) {
                const int dd = c0 * 4 + ddl;
                const v4 e0 = *(const v4*)&dTs[p][dd * BC + tx * 4];
                const v4 e1 = *(const v4*)&dTs[p][dd * BC + 64 + tx * 4];
                const v4 e2 = *(const v4*)&dTs[p][dd * BC + 128 + tx * 4];
                const v4 e3 = *(const v4*)&dTs[p][dd * BC + 192 + tx * 4];
                const float ec[16] = {e0[0], e0[1], e0[2], e0[3],
                                      e1[0], e1[1], e1[2], e1[3],
                                      e2[0], e2[1], e2[2], e2[3],
                                      e3[0], e3[1], e3[2], e3[3]};
                #pragma unroll
                for (int r = 0; r < 8; ++r) {
                    const float frv = fq[r][ddl];
                    #pragma unroll
                    for (int j = 0; j < 16; ++j)
                        acc[r][j] = fmaf(frv, ec[j], acc[r][j]);
                }
            }
        }
        if ((s & 15) == 15) {
            // dist = fl( fl(A + B) - 2*s ) — np rounding chain (fma of
            // t1 - 2*acc bit-identical: 2*acc exact). Codes ascend with
            // (ct, j) for fixed tx -> strict < keeps FIRST min index.
            const int cbase = (s >> 4) * BC;
            float en[16];
            #pragma unroll
            for (int j = 0; j < 16; ++j)
                en[j] = enorm[cbase + (j >> 2) * 64 + tx * 4 + (j & 3)];
            #pragma unroll
            for (int r = 0; r < 8; ++r)
                #pragma unroll
                for (int j = 0; j < 16; ++j) {
                    int code = cbase + (j >> 2) * 64 + tx * 4 + (j & 3);
                    float t1 = Arow[r] + en[j];
                    float dist = t1 - 2.0f * acc[r][j];
                    if (dist < minv[r]) { minv[r] = dist; mini[r] = code; }
                }
        }
        __syncthreads();
    }

    // Cross-lane argmin over the 16 tx lanes (xor<16 stays in-wave; lane =
    // (ty&3)*16 + tx). Tie -> smaller index (first occurrence).
    #pragma unroll
    for (int m = 1; m < 16; m <<= 1)
        #pragma unroll
        for (int r = 0; r < 8; ++r) {
            float ov = __shfl_xor(minv[r], m, 64);
            int   oi = __shfl_xor(mini[r], m, 64);
            if (ov < minv[r] || (ov == minv[r] && oi < mini[r])) {
                minv[r] = ov; mini[r] = oi;
            }
        }

    int* idx_s = (int*)&dTs[0][0];       // step-63 read dTs[1]; dTs[0] free
    if (tx == 0) {
        #pragma unroll
        for (int r = 0; r < 8; ++r) idx_s[ty * 8 + r] = mini[r];
    }
    __syncthreads();

    // Epilogue: gather codebook row (dictT L2-resident), re-read x (L3-hot),
    // emulate STE out = fl(x + fl(q-x)), loss on pure q (before STE).
    // unroll 2 = load ILP; lsum chain order preserved (no reassociation).
    // Nontemporal store: out is write-only, skip L2 RFO.
    float lsum = 0.f;
    {
#pragma clang fp contract(off)
        #pragma unroll 2
        for (int i = 0; i < BM; ++i) {
            int k = idx_s[i];
            float qv = dictT[(size_t)k * DDIM + tid];
            float xv = x[(size_t)(rowbase + i) * DDIM + tid];
            float diff = qv - xv;                                 // fl(q - x)
            __builtin_nontemporal_store(xv + diff,
                &out[(size_t)(rowbase + i) * DDIM + tid]);        // fl(x + fl(q-x))
            float d = xv - qv;
            float dsq = d * d;
            lsum = lsum + dsq;
        }
    }
    #pragma unroll
    for (int off = 32; off > 0; off >>= 1)
        lsum += __shfl_down(lsum, off, 64);
    if ((tid & 63) == 0)
        atomicAdd(loss, lsum * (1.25f / 16777216.0f));  // (1+BETA)/(N*D)
}

extern "C" void kernel_launch(void* const* d_in, const int* in_sizes, int n_in,
                              void* d_out, int out_size, void* d_ws, size_t ws_size,
                              hipStream_t stream) {
    (void)in_sizes; (void)n_in; (void)out_size; (void)ws_size;
    const float* x    = (const float*)d_in[0];
    const float* dict = (const float*)d_in[1];
    float* out   = (float*)d_out;
    float* enorm = (float*)d_ws;                 // 1024 floats
    float* dictT = enorm + KC;                   // 1024*256 floats (1 MB)
    float* loss  = out + (size_t)NROWS * DDIM;   // scalar slot after q

    vq_prep<<<KC / 64, 64, 0, stream>>>(dict, enorm, dictT, loss);
    vq_main<<<NROWS / BM, 256, 0, stream>>>(x, dict, enorm, dictT, out, loss);
}